// Round 4
// baseline (107522.705 us; speedup 1.0000x reference)
//
#include <hip/hip_runtime.h>
#include <hip/hip_bf16.h>

#define VOCAB 200000
#define EMB 256
#define HID 512
#define SEQ 8192
#define TOK 32768
#define TAGS 512
#define G4H 2048  // 4*HID

#define SENT 0x7FBFFFFFu  // NaN payload sentinel; real h/xg always finite

typedef float f8v __attribute__((ext_vector_type(8)));

__device__ __forceinline__ float sigmoidf_(float x) { return 1.0f / (1.0f + __expf(-x)); }
__device__ __forceinline__ float tanhf_(float x) { return 1.0f - 2.0f / (1.0f + __expf(2.0f * x)); }

// ---------------- kernel 0: sentinel init (hbuf + xcd table) -----------------
__global__ void init_sentinel(unsigned* __restrict__ hbuf, int n,
                              unsigned* __restrict__ tab, int ntab) {
  int i = blockIdx.x * blockDim.x + threadIdx.x;
  int stride = gridDim.x * blockDim.x;
  for (int k = i; k < n; k += stride) hbuf[k] = SENT;
  for (int k = i; k < ntab; k += stride) tab[k] = 0xFFFFFFFFu;
}

// ---------------- kernel 1: embedding bag (sum pool per sorted segment) ------
__global__ __launch_bounds__(256) void embed_pool(
    const float* __restrict__ emb, const int* __restrict__ ids,
    const int* __restrict__ seg, float* __restrict__ out) {
  int s = blockIdx.x;
  int d = threadIdx.x;  // 256 = EMB
  int lo = 0, hi = TOK;
  while (lo < hi) { int m = (lo + hi) >> 1; if (seg[m] < s) lo = m + 1; else hi = m; }
  int start = lo;
  hi = TOK;
  while (lo < hi) { int m = (lo + hi) >> 1; if (seg[m] < s + 1) lo = m + 1; else hi = m; }
  int end = lo;
  float acc = 0.f;
  for (int tkn = start; tkn < end; ++tkn) {
    acc += emb[(long)ids[tkn] * EMB + d];
  }
  out[s * EMB + d] = acc;
}

// ---------------- kernel 2: xg = embeds @ w_ih^T + b  (both dirs) ------------
__global__ __launch_bounds__(256) void xg_gemm(
    const float* __restrict__ embeds,
    const float* __restrict__ w_ih_f, const float* __restrict__ b_f,
    const float* __restrict__ w_ih_b, const float* __restrict__ b_b,
    float* __restrict__ xg) {
  int dir = blockIdx.z;
  const float* W = dir ? w_ih_b : w_ih_f;
  const float* B = dir ? b_b : b_f;
  float* out = xg + (size_t)dir * SEQ * G4H;
  int j0 = blockIdx.x * 64, t0 = blockIdx.y * 64;
  __shared__ float As[64][65];
  __shared__ float Bs[64][65];
  int tid = threadIdx.x;
  int ty = tid >> 4, tx = tid & 15;
  float acc[4][4] = {};
  for (int kc = 0; kc < EMB; kc += 64) {
#pragma unroll
    for (int i = 0; i < 4; ++i) {
      int fi = tid * 4 + i;
      int r = fi >> 4, c4 = fi & 15;
      float4 a = *(const float4*)&embeds[(size_t)(t0 + r) * EMB + kc + c4 * 4];
      As[r][c4 * 4 + 0] = a.x; As[r][c4 * 4 + 1] = a.y;
      As[r][c4 * 4 + 2] = a.z; As[r][c4 * 4 + 3] = a.w;
      float4 b = *(const float4*)&W[(size_t)(j0 + r) * EMB + kc + c4 * 4];
      Bs[r][c4 * 4 + 0] = b.x; Bs[r][c4 * 4 + 1] = b.y;
      Bs[r][c4 * 4 + 2] = b.z; Bs[r][c4 * 4 + 3] = b.w;
    }
    __syncthreads();
#pragma unroll 8
    for (int kk = 0; kk < 64; ++kk) {
      float a[4], b[4];
#pragma unroll
      for (int i = 0; i < 4; ++i) a[i] = As[ty * 4 + i][kk];
#pragma unroll
      for (int i = 0; i < 4; ++i) b[i] = Bs[tx * 4 + i][kk];
#pragma unroll
      for (int i = 0; i < 4; ++i)
#pragma unroll
        for (int j = 0; j < 4; ++j) acc[i][j] = fmaf(a[i], b[j], acc[i][j]);
    }
    __syncthreads();
  }
#pragma unroll
  for (int i = 0; i < 4; ++i)
#pragma unroll
    for (int j = 0; j < 4; ++j)
      out[(size_t)(t0 + ty * 4 + i) * G4H + j0 + tx * 4 + j] = acc[i][j] + B[j0 + tx * 4 + j];
}

// ---------------- kernel 3: XCD-local bidirectional LSTM scan ----------------
// Grid 2048 x 64thr; workers are blocks with b%8 in {0,1} (under the HW's
// round-robin block->XCD heuristic, dir0 workers all land on XCD0, dir1 on
// XCD1). Worker Wk = b>>3 owns h {2Wk, 2Wk+1}. Lane covers 8 gate rows x
// cols {lane+64u}. Weights in named f8v VGPRs (asm-pinned). Polls: fast
// sc0 (L2) when all producers verified same-XCD via s_getreg(XCC_ID)
// election table, else agent-scope (L3). Bounded fast tries -> always safe.
#define LOADW(M, G_, Q_) \
  { const float* wr = W + (size_t)(512 * (G_) + k0 + (Q_)) * HID + lane; \
    w##M[0] = wr[0];   w##M[1] = wr[64];  w##M[2] = wr[128]; w##M[3] = wr[192]; \
    w##M[4] = wr[256]; w##M[5] = wr[320]; w##M[6] = wr[384]; w##M[7] = wr[448]; }

#define DOT(M, DST) \
  { float a_ = w##M[0] * hv[0]; \
    a_ = fmaf(w##M[1], hv[1], a_); a_ = fmaf(w##M[2], hv[2], a_); \
    a_ = fmaf(w##M[3], hv[3], a_); a_ = fmaf(w##M[4], hv[4], a_); \
    a_ = fmaf(w##M[5], hv[5], a_); a_ = fmaf(w##M[6], hv[6], a_); \
    a_ = fmaf(w##M[7], hv[7], a_); DST = a_; }

#define PINW() asm volatile("" : "+v"(w0), "+v"(w1), "+v"(w2), "+v"(w3), \
                                 "+v"(w4), "+v"(w5), "+v"(w6), "+v"(w7))

__global__ __launch_bounds__(64, 2) void lstm_scan(
    const float* __restrict__ w_hh_f, const float* __restrict__ w_hh_b,
    const float* __restrict__ xg, unsigned* __restrict__ hbuf,
    unsigned* __restrict__ xcdtab) {
  int b = blockIdx.x;
  int sel = b & 7;
  if (sel >= 2) return;  // non-worker block
  int dir = sel;
  int Wk = b >> 3;  // 0..255
  const float* W = dir ? w_hh_b : w_hh_f;
  const float* xgd = xg + (size_t)dir * SEQ * G4H;
  unsigned* hb = hbuf + (size_t)dir * SEQ * HID;

  int lane = threadIdx.x;  // 0..63
  const int q = lane & 1;
  const int k0 = 2 * Wk;

  // publish my XCD id (HW_REG_XCC_ID = hwreg 20)
  int my_xcd = (int)(__builtin_amdgcn_s_getreg(20 | (31 << 11)) & 0xFu);
  if (lane == 0)
    __hip_atomic_store(&xcdtab[dir * 256 + Wk], (unsigned)my_xcd,
                       __ATOMIC_RELAXED, __HIP_MEMORY_SCOPE_AGENT);

  // preload weight slice into named vector regs (rows 512g + k0 + q')
  f8v w0, w1, w2, w3, w4, w5, w6, w7;  // m = 2g + q'
  LOADW(0, 0, 0) LOADW(1, 0, 1) LOADW(2, 1, 0) LOADW(3, 1, 1)
  LOADW(4, 2, 0) LOADW(5, 2, 1) LOADW(6, 3, 0) LOADW(7, 3, 1)
  PINW();

  // election read-back: are ALL producers of my direction on my XCD?
  bool same = true;
  for (int p = lane; p < 256; p += 64) {
    unsigned v;
    for (;;) {
      v = __hip_atomic_load(&xcdtab[dir * 256 + p], __ATOMIC_RELAXED,
                            __HIP_MEMORY_SCOPE_AGENT);
      if (v != 0xFFFFFFFFu) break;
      __builtin_amdgcn_s_sleep(2);
    }
    same &= (v == (unsigned)my_xcd);
  }
  same = __all((int)same);

  float cst = 0.f;  // cell state for h[k0+q] (lane-parity redundant)

  for (int t = 0; t < SEQ; ++t) {
    int tt = dir ? (SEQ - 1 - t) : t;

    // xg contribution for my 4 gate rows (issue before poll; overlaps it)
    const float* xrow = xgd + (size_t)tt * G4H + k0 + q;
    float xv0 = xrow[0], xv1 = xrow[512], xv2 = xrow[1024], xv3 = xrow[1536];

    float hv[8];
    if (t == 0) {
#pragma unroll
      for (int u = 0; u < 8; ++u) hv[u] = 0.f;
    } else {
      int pt = dir ? (tt + 1) : (tt - 1);
      const unsigned* src = hb + (size_t)pt * HID + lane;
      unsigned u0, u1, u2, u3, u4, u5, u6, u7;
      bool got = false;
      if (same) {
        for (int tries = 0; tries < 64 && !got; ++tries) {
          asm volatile(
              "global_load_dword %0, %8, off sc0\n\t"
              "global_load_dword %1, %8, off offset:256 sc0\n\t"
              "global_load_dword %2, %8, off offset:512 sc0\n\t"
              "global_load_dword %3, %8, off offset:768 sc0\n\t"
              "global_load_dword %4, %8, off offset:1024 sc0\n\t"
              "global_load_dword %5, %8, off offset:1280 sc0\n\t"
              "global_load_dword %6, %8, off offset:1536 sc0\n\t"
              "global_load_dword %7, %8, off offset:1792 sc0\n\t"
              "s_waitcnt vmcnt(0)"
              : "=&v"(u0), "=&v"(u1), "=&v"(u2), "=&v"(u3),
                "=&v"(u4), "=&v"(u5), "=&v"(u6), "=&v"(u7)
              : "v"(src)
              : "memory");
          bool ok = (u0 != SENT) & (u1 != SENT) & (u2 != SENT) & (u3 != SENT) &
                    (u4 != SENT) & (u5 != SENT) & (u6 != SENT) & (u7 != SENT);
          got = __all((int)ok);
        }
      }
      while (!got) {  // safe agent-scope (L3) path; always correct
        u0 = __hip_atomic_load(&src[0],   __ATOMIC_RELAXED, __HIP_MEMORY_SCOPE_AGENT);
        u1 = __hip_atomic_load(&src[64],  __ATOMIC_RELAXED, __HIP_MEMORY_SCOPE_AGENT);
        u2 = __hip_atomic_load(&src[128], __ATOMIC_RELAXED, __HIP_MEMORY_SCOPE_AGENT);
        u3 = __hip_atomic_load(&src[192], __ATOMIC_RELAXED, __HIP_MEMORY_SCOPE_AGENT);
        u4 = __hip_atomic_load(&src[256], __ATOMIC_RELAXED, __HIP_MEMORY_SCOPE_AGENT);
        u5 = __hip_atomic_load(&src[320], __ATOMIC_RELAXED, __HIP_MEMORY_SCOPE_AGENT);
        u6 = __hip_atomic_load(&src[384], __ATOMIC_RELAXED, __HIP_MEMORY_SCOPE_AGENT);
        u7 = __hip_atomic_load(&src[448], __ATOMIC_RELAXED, __HIP_MEMORY_SCOPE_AGENT);
        bool ok = (u0 != SENT) & (u1 != SENT) & (u2 != SENT) & (u3 != SENT) &
                  (u4 != SENT) & (u5 != SENT) & (u6 != SENT) & (u7 != SENT);
        got = __all((int)ok);
        if (!got) __builtin_amdgcn_s_sleep(1);
      }
      hv[0] = __uint_as_float(u0); hv[1] = __uint_as_float(u1);
      hv[2] = __uint_as_float(u2); hv[3] = __uint_as_float(u3);
      hv[4] = __uint_as_float(u4); hv[5] = __uint_as_float(u5);
      hv[6] = __uint_as_float(u6); hv[7] = __uint_as_float(u7);
    }

    PINW();  // keep weights resident; no code emitted

    // matvec partials: 8 rows x 8 cols per lane
    float ss[8];
    DOT(0, ss[0]) DOT(1, ss[1]) DOT(2, ss[2]) DOT(3, ss[3])
    DOT(4, ss[4]) DOT(5, ss[5]) DOT(6, ss[6]) DOT(7, ss[7])

    // reduce: fold q-pair via xor1 exchange, then full butterfly on 4 values
    float t4[4];
    {
      const bool lo1 = (lane & 1) != 0;
#pragma unroll
      for (int g = 0; g < 4; ++g) {
        float a = ss[2 * g + 0], c = ss[2 * g + 1];
        float own = lo1 ? c : a;
        float oth = lo1 ? a : c;
        t4[g] = own + __shfl_xor(oth, 1);
      }
#pragma unroll
      for (int g = 0; g < 4; ++g) {
        float v = t4[g];
        v += __shfl_xor(v, 2);
        v += __shfl_xor(v, 4);
        v += __shfl_xor(v, 8);
        v += __shfl_xor(v, 16);
        v += __shfl_xor(v, 32);
        t4[g] = v;
      }
    }

    // gates (all lanes compute for their parity q; uniform control flow)
    float gi = t4[0] + xv0;
    float gf = t4[1] + xv1;
    float gg = t4[2] + xv2;
    float go = t4[3] + xv3;
    float iv = sigmoidf_(gi), fv = sigmoidf_(gf), gv = tanhf_(gg), ov = sigmoidf_(go);
    cst = fv * cst + iv * gv;
    float h = ov * tanhf_(cst);
    if (lane < 2) {  // lane == q here
      __hip_atomic_store(hb + (size_t)tt * HID + k0 + lane, __float_as_uint(h),
                         __ATOMIC_RELAXED, __HIP_MEMORY_SCOPE_AGENT);
    }
  }
}

// ---------------- kernel 4: logits = h_cat @ w_out^T + b_out -----------------
__global__ __launch_bounds__(256) void out_gemm(
    const unsigned* __restrict__ hbuf, const float* __restrict__ w_out,
    const float* __restrict__ b_out, float* __restrict__ out) {
  int j0 = blockIdx.x * 128, t0 = blockIdx.y * 64;
  __shared__ float hs[64][65];
  __shared__ float ws_[128][65];
  int tid = threadIdx.x;
  int ti = tid & 15, ji = tid >> 4;
  float acc[4][8] = {};
  const float* hf = (const float*)hbuf;
  for (int kc = 0; kc < 1024; kc += 64) {
    const float* hsrc = (kc < 512) ? hf : (hf + (size_t)SEQ * HID);
    int kb = kc & 511;
#pragma unroll
    for (int i = 0; i < 4; ++i) {
      int fi = tid * 4 + i;
      int r = fi >> 4, c4 = fi & 15;
      float4 v = *(const float4*)&hsrc[(size_t)(t0 + r) * HID + kb + c4 * 4];
      hs[r][c4 * 4 + 0] = v.x; hs[r][c4 * 4 + 1] = v.y;
      hs[r][c4 * 4 + 2] = v.z; hs[r][c4 * 4 + 3] = v.w;
    }
#pragma unroll
    for (int i = 0; i < 8; ++i) {
      int fi = tid * 8 + i;
      int r = fi >> 4, c4 = fi & 15;
      float4 v = *(const float4*)&w_out[(size_t)(j0 + r) * 1024 + kc + c4 * 4];
      ws_[r][c4 * 4 + 0] = v.x; ws_[r][c4 * 4 + 1] = v.y;
      ws_[r][c4 * 4 + 2] = v.z; ws_[r][c4 * 4 + 3] = v.w;
    }
    __syncthreads();
#pragma unroll 4
    for (int kk = 0; kk < 64; ++kk) {
      float a[4], b[8];
#pragma unroll
      for (int x = 0; x < 4; ++x) a[x] = hs[ti * 4 + x][kk];
#pragma unroll
      for (int y = 0; y < 8; ++y) b[y] = ws_[ji * 8 + y][kk];
#pragma unroll
      for (int x = 0; x < 4; ++x)
#pragma unroll
        for (int y = 0; y < 8; ++y) acc[x][y] = fmaf(a[x], b[y], acc[x][y]);
    }
    __syncthreads();
  }
#pragma unroll
  for (int x = 0; x < 4; ++x)
#pragma unroll
    for (int y = 0; y < 8; ++y)
      out[(size_t)(t0 + ti * 4 + x) * TAGS + j0 + ji * 8 + y] = acc[x][y] + b_out[j0 + ji * 8 + y];
}

// ---------------- kernel 5: row-wise log_softmax in place --------------------
__global__ __launch_bounds__(256) void logsoftmax(float* __restrict__ out) {
  int t = blockIdx.x;
  float* row = out + (size_t)t * TAGS;
  int tid = threadIdx.x;
  float a = row[tid], b = row[tid + 256];
  float m = fmaxf(a, b);
  m = fmaxf(m, __shfl_xor(m, 1));
  m = fmaxf(m, __shfl_xor(m, 2));
  m = fmaxf(m, __shfl_xor(m, 4));
  m = fmaxf(m, __shfl_xor(m, 8));
  m = fmaxf(m, __shfl_xor(m, 16));
  m = fmaxf(m, __shfl_xor(m, 32));
  __shared__ float redm[4];
  __shared__ float reds[4];
  int wv = tid >> 6;
  if ((tid & 63) == 0) redm[wv] = m;
  __syncthreads();
  m = fmaxf(fmaxf(redm[0], redm[1]), fmaxf(redm[2], redm[3]));
  float s = __expf(a - m) + __expf(b - m);
  s += __shfl_xor(s, 1);
  s += __shfl_xor(s, 2);
  s += __shfl_xor(s, 4);
  s += __shfl_xor(s, 8);
  s += __shfl_xor(s, 16);
  s += __shfl_xor(s, 32);
  if ((tid & 63) == 0) reds[wv] = s;
  __syncthreads();
  s = reds[0] + reds[1] + reds[2] + reds[3];
  float ls = m + __logf(s);
  row[tid] = a - ls;
  row[tid + 256] = b - ls;
}

extern "C" void kernel_launch(void* const* d_in, const int* in_sizes, int n_in,
                              void* d_out, int out_size, void* d_ws, size_t ws_size,
                              hipStream_t stream) {
  (void)in_sizes; (void)n_in; (void)out_size; (void)ws_size;
  const float* emb    = (const float*)d_in[0];
  const float* w_ih_f = (const float*)d_in[1];
  const float* w_hh_f = (const float*)d_in[2];
  const float* b_f    = (const float*)d_in[3];
  const float* w_ih_b = (const float*)d_in[4];
  const float* w_hh_b = (const float*)d_in[5];
  const float* b_b    = (const float*)d_in[6];
  const float* w_out  = (const float*)d_in[7];
  const float* b_out  = (const float*)d_in[8];
  const int*   ids    = (const int*)d_in[9];
  const int*   seg    = (const int*)d_in[10];
  float* out = (float*)d_out;

  char* ws = (char*)d_ws;
  float*    embeds = (float*)ws;                                       // 8 MB
  float*    xg     = (float*)(ws + (8ll << 20));                       // 128 MB
  unsigned* hbuf   = (unsigned*)(ws + (8ll << 20) + (128ll << 20));    // 32 MB
  // election table lives in d_out scratch (fully overwritten by out_gemm later)
  unsigned* xcdtab = (unsigned*)d_out;                                 // 512 words

  init_sentinel<<<2048, 256, 0, stream>>>(hbuf, 2 * SEQ * HID, xcdtab, 512);
  embed_pool<<<SEQ, 256, 0, stream>>>(emb, ids, seg, embeds);
  dim3 g2(G4H / 64, SEQ / 64, 2);
  xg_gemm<<<g2, 256, 0, stream>>>(embeds, w_ih_f, b_f, w_ih_b, b_b, xg);
  lstm_scan<<<2048, 64, 0, stream>>>(w_hh_f, w_hh_b, xg, hbuf, xcdtab);
  dim3 g4(TAGS / 128, SEQ / 64);
  out_gemm<<<g4, 256, 0, stream>>>(hbuf, w_out, b_out, out);
  logsoftmax<<<SEQ, 256, 0, stream>>>(out);
}

// Round 5
// 21803.381 us; speedup vs baseline: 4.9315x; 4.9315x over previous
//
#include <hip/hip_runtime.h>
#include <hip/hip_bf16.h>

#define VOCAB 200000
#define EMB 256
#define HID 512
#define SEQ 8192
#define TOK 32768
#define TAGS 512
#define G4H 2048  // 4*HID

#define SENT 0x7FBFFFFFu  // NaN payload sentinel; real h is always finite

typedef unsigned u4v __attribute__((ext_vector_type(4)));

__device__ __forceinline__ float sigmoidf_(float x) { return 1.0f / (1.0f + __expf(-x)); }
__device__ __forceinline__ float tanhf_(float x) { return 1.0f - 2.0f / (1.0f + __expf(2.0f * x)); }

// ---------------- kernel 0: sentinel init for h buffer -----------------------
__global__ void init_sentinel(unsigned* __restrict__ hbuf, int n) {
  int i = blockIdx.x * blockDim.x + threadIdx.x;
  int stride = gridDim.x * blockDim.x;
  for (int k = i; k < n; k += stride) hbuf[k] = SENT;
}

// ---------------- kernel 1: embedding bag (sum pool per sorted segment) ------
__global__ __launch_bounds__(256) void embed_pool(
    const float* __restrict__ emb, const int* __restrict__ ids,
    const int* __restrict__ seg, float* __restrict__ out) {
  int s = blockIdx.x;
  int d = threadIdx.x;  // 256 = EMB
  int lo = 0, hi = TOK;
  while (lo < hi) { int m = (lo + hi) >> 1; if (seg[m] < s) lo = m + 1; else hi = m; }
  int start = lo;
  hi = TOK;
  while (lo < hi) { int m = (lo + hi) >> 1; if (seg[m] < s + 1) lo = m + 1; else hi = m; }
  int end = lo;
  float acc = 0.f;
  for (int tkn = start; tkn < end; ++tkn) {
    acc += emb[(long)ids[tkn] * EMB + d];
  }
  out[s * EMB + d] = acc;
}

// ---------------- kernel 2: xg = embeds @ w_ih^T + b  (both dirs) ------------
__global__ __launch_bounds__(256) void xg_gemm(
    const float* __restrict__ embeds,
    const float* __restrict__ w_ih_f, const float* __restrict__ b_f,
    const float* __restrict__ w_ih_b, const float* __restrict__ b_b,
    float* __restrict__ xg) {
  int dir = blockIdx.z;
  const float* W = dir ? w_ih_b : w_ih_f;
  const float* B = dir ? b_b : b_f;
  float* out = xg + (size_t)dir * SEQ * G4H;
  int j0 = blockIdx.x * 64, t0 = blockIdx.y * 64;
  __shared__ float As[64][65];
  __shared__ float Bs[64][65];
  int tid = threadIdx.x;
  int ty = tid >> 4, tx = tid & 15;
  float acc[4][4] = {};
  for (int kc = 0; kc < EMB; kc += 64) {
#pragma unroll
    for (int i = 0; i < 4; ++i) {
      int fi = tid * 4 + i;
      int r = fi >> 4, c4 = fi & 15;
      float4 a = *(const float4*)&embeds[(size_t)(t0 + r) * EMB + kc + c4 * 4];
      As[r][c4 * 4 + 0] = a.x; As[r][c4 * 4 + 1] = a.y;
      As[r][c4 * 4 + 2] = a.z; As[r][c4 * 4 + 3] = a.w;
      float4 b = *(const float4*)&W[(size_t)(j0 + r) * EMB + kc + c4 * 4];
      Bs[r][c4 * 4 + 0] = b.x; Bs[r][c4 * 4 + 1] = b.y;
      Bs[r][c4 * 4 + 2] = b.z; Bs[r][c4 * 4 + 3] = b.w;
    }
    __syncthreads();
#pragma unroll 8
    for (int kk = 0; kk < 64; ++kk) {
      float a[4], b[4];
#pragma unroll
      for (int i = 0; i < 4; ++i) a[i] = As[ty * 4 + i][kk];
#pragma unroll
      for (int i = 0; i < 4; ++i) b[i] = Bs[tx * 4 + i][kk];
#pragma unroll
      for (int i = 0; i < 4; ++i)
#pragma unroll
        for (int j = 0; j < 4; ++j) acc[i][j] = fmaf(a[i], b[j], acc[i][j]);
    }
    __syncthreads();
  }
#pragma unroll
  for (int i = 0; i < 4; ++i)
#pragma unroll
    for (int j = 0; j < 4; ++j)
      out[(size_t)(t0 + ty * 4 + i) * G4H + j0 + tx * 4 + j] = acc[i][j] + B[j0 + tx * 4 + j];
}

// ---------------- kernel 3: single-wave-WG bidirectional LSTM scan -----------
// 256 WGs x 64 threads. dir = b>>7, wb = b&127 owns h [4wb, 4wb+4).
// LDS: W slice [16 rows][512 cols] = 32KB; LDS row r <-> global gate row
// 512*(r>>2) + 4*wb + (r&3)  (gate g = r>>2, h-offset hh = r&3).
// Per step: lane polls h[4*lane..+3] and h[256+4*lane..+3] (coalesced 1KB,
// sc0 sc1 = L3-coherent), 32x ds_read_b128 W + 128 FMA -> acc[16],
// log-fold shfl reduce (17 shfls) -> lane holds row (lane&15) sum,
// 4 shfl gather -> all lanes compute gates for hh=lane&3, lanes 0-3 store.
// No barriers in the loop; nothing register-pinned (weights live in LDS).
__global__ __launch_bounds__(64) void lstm_scan(
    const float* __restrict__ w_hh_f, const float* __restrict__ w_hh_b,
    const float* __restrict__ xg, unsigned* __restrict__ hbuf) {
  int b = blockIdx.x;
  int dir = b >> 7;
  int wb = b & 127;
  const float* W = dir ? w_hh_b : w_hh_f;
  const float* xgd = xg + (size_t)dir * SEQ * G4H;
  unsigned* hb = hbuf + (size_t)dir * SEQ * HID;

  int lane = threadIdx.x;  // 0..63
  const int hh = lane & 3;
  const int k0 = 4 * wb;

  __shared__ float4 Wl[16 * 128];  // float4 idx = r*128 + hf*64 + l  (dword 512r+256hf+4l)
  for (int idx = lane; idx < 16 * 128; idx += 64) {
    int r = idx >> 7, c4 = idx & 127;
    int gr = 512 * (r >> 2) + k0 + (r & 3);
    Wl[idx] = *(const float4*)&W[(size_t)gr * HID + 4 * c4];
  }
  __syncthreads();

  float cst = 0.f;  // cell state for h[k0+hh] (redundant across 16-lane groups)

  for (int t = 0; t < SEQ; ++t) {
    int tt = dir ? (SEQ - 1 - t) : t;

    // xg contributions for my hh's 4 gates (issued early; overlaps the poll)
    const float* xrow = xgd + (size_t)tt * G4H + k0 + hh;
    float xv0 = xrow[0], xv1 = xrow[512], xv2 = xrow[1024], xv3 = xrow[1536];

    // poll h_prev: lane needs exactly cols {4l..4l+3} and {256+4l..256+4l+3}
    float4 h0, h1;
    if (t == 0) {
      h0 = make_float4(0.f, 0.f, 0.f, 0.f);
      h1 = make_float4(0.f, 0.f, 0.f, 0.f);
    } else {
      int pt = dir ? (tt + 1) : (tt - 1);
      const unsigned* src = hb + (size_t)pt * HID + 4 * lane;
      u4v a, c;
      for (;;) {
        asm volatile(
            "global_load_dwordx4 %0, %2, off sc0 sc1\n\t"
            "global_load_dwordx4 %1, %2, off offset:1024 sc0 sc1\n\t"
            "s_waitcnt vmcnt(0)"
            : "=&v"(a), "=&v"(c)
            : "v"(src)
            : "memory");
        bool ok = (a.x != SENT) & (a.y != SENT) & (a.z != SENT) & (a.w != SENT) &
                  (c.x != SENT) & (c.y != SENT) & (c.z != SENT) & (c.w != SENT);
        if (__all((int)ok)) break;
        __builtin_amdgcn_s_sleep(1);
      }
      h0.x = __uint_as_float(a.x); h0.y = __uint_as_float(a.y);
      h0.z = __uint_as_float(a.z); h0.w = __uint_as_float(a.w);
      h1.x = __uint_as_float(c.x); h1.y = __uint_as_float(c.y);
      h1.z = __uint_as_float(c.z); h1.w = __uint_as_float(c.w);
    }

    // matvec partials: acc[r] = sum over my 8 cols of W[r][c]*h[c]
    float acc[16];
#pragma unroll
    for (int r = 0; r < 16; ++r) {
      float4 wa = Wl[r * 128 + lane];
      float4 wc = Wl[r * 128 + 64 + lane];
      float a_ = wa.x * h0.x;
      a_ = fmaf(wa.y, h0.y, a_);
      a_ = fmaf(wa.z, h0.z, a_);
      a_ = fmaf(wa.w, h0.w, a_);
      a_ = fmaf(wc.x, h1.x, a_);
      a_ = fmaf(wc.y, h1.y, a_);
      a_ = fmaf(wc.z, h1.z, a_);
      a_ = fmaf(wc.w, h1.w, a_);
      acc[r] = a_;
    }

    // log-fold butterfly: 17 shfls total; ends with lane holding row lane&15
    float v8[8];
    {
      int b0 = lane & 1;
#pragma unroll
      for (int j = 0; j < 8; ++j) {
        float mine = b0 ? acc[2 * j + 1] : acc[2 * j];
        float oth  = b0 ? acc[2 * j] : acc[2 * j + 1];
        v8[j] = mine + __shfl_xor(oth, 1);
      }
    }
    float v4[4];
    {
      int b1 = (lane >> 1) & 1;
#pragma unroll
      for (int j = 0; j < 4; ++j) {
        float mine = b1 ? v8[2 * j + 1] : v8[2 * j];
        float oth  = b1 ? v8[2 * j] : v8[2 * j + 1];
        v4[j] = mine + __shfl_xor(oth, 2);
      }
    }
    float v2[2];
    {
      int b2 = (lane >> 2) & 1;
#pragma unroll
      for (int j = 0; j < 2; ++j) {
        float mine = b2 ? v4[2 * j + 1] : v4[2 * j];
        float oth  = b2 ? v4[2 * j] : v4[2 * j + 1];
        v2[j] = mine + __shfl_xor(oth, 4);
      }
    }
    float v1;
    {
      int b3 = (lane >> 3) & 1;
      float mine = b3 ? v2[1] : v2[0];
      float oth  = b3 ? v2[0] : v2[1];
      v1 = mine + __shfl_xor(oth, 8);
      v1 += __shfl_xor(v1, 16);
      v1 += __shfl_xor(v1, 32);
    }

    // gather the 4 gate sums for my hh (rows 4g+hh live in lanes 4g+hh)
    float si = __shfl(v1, hh + 0)  + xv0;
    float sf = __shfl(v1, hh + 4)  + xv1;
    float sg = __shfl(v1, hh + 8)  + xv2;
    float so = __shfl(v1, hh + 12) + xv3;

    float iv = sigmoidf_(si), fv = sigmoidf_(sf), gv = tanhf_(sg), ov = sigmoidf_(so);
    cst = fv * cst + iv * gv;
    float h = ov * tanhf_(cst);
    if (lane < 4) {  // lane == hh here
      __hip_atomic_store(hb + (size_t)tt * HID + k0 + lane, __float_as_uint(h),
                         __ATOMIC_RELAXED, __HIP_MEMORY_SCOPE_AGENT);
    }
  }
}

// ---------------- kernel 4: logits = h_cat @ w_out^T + b_out -----------------
__global__ __launch_bounds__(256) void out_gemm(
    const unsigned* __restrict__ hbuf, const float* __restrict__ w_out,
    const float* __restrict__ b_out, float* __restrict__ out) {
  int j0 = blockIdx.x * 128, t0 = blockIdx.y * 64;
  __shared__ float hs[64][65];
  __shared__ float ws_[128][65];
  int tid = threadIdx.x;
  int ti = tid & 15, ji = tid >> 4;
  float acc[4][8] = {};
  const float* hf = (const float*)hbuf;
  for (int kc = 0; kc < 1024; kc += 64) {
    const float* hsrc = (kc < 512) ? hf : (hf + (size_t)SEQ * HID);
    int kb = kc & 511;
#pragma unroll
    for (int i = 0; i < 4; ++i) {
      int fi = tid * 4 + i;
      int r = fi >> 4, c4 = fi & 15;
      float4 v = *(const float4*)&hsrc[(size_t)(t0 + r) * HID + kb + c4 * 4];
      hs[r][c4 * 4 + 0] = v.x; hs[r][c4 * 4 + 1] = v.y;
      hs[r][c4 * 4 + 2] = v.z; hs[r][c4 * 4 + 3] = v.w;
    }
#pragma unroll
    for (int i = 0; i < 8; ++i) {
      int fi = tid * 8 + i;
      int r = fi >> 4, c4 = fi & 15;
      float4 v = *(const float4*)&w_out[(size_t)(j0 + r) * 1024 + kc + c4 * 4];
      ws_[r][c4 * 4 + 0] = v.x; ws_[r][c4 * 4 + 1] = v.y;
      ws_[r][c4 * 4 + 2] = v.z; ws_[r][c4 * 4 + 3] = v.w;
    }
    __syncthreads();
#pragma unroll 4
    for (int kk = 0; kk < 64; ++kk) {
      float a[4], b[8];
#pragma unroll
      for (int x = 0; x < 4; ++x) a[x] = hs[ti * 4 + x][kk];
#pragma unroll
      for (int y = 0; y < 8; ++y) b[y] = ws_[ji * 8 + y][kk];
#pragma unroll
      for (int x = 0; x < 4; ++x)
#pragma unroll
        for (int y = 0; y < 8; ++y) acc[x][y] = fmaf(a[x], b[y], acc[x][y]);
    }
    __syncthreads();
  }
#pragma unroll
  for (int x = 0; x < 4; ++x)
#pragma unroll
    for (int y = 0; y < 8; ++y)
      out[(size_t)(t0 + ti * 4 + x) * TAGS + j0 + ji * 8 + y] = acc[x][y] + b_out[j0 + ji * 8 + y];
}

// ---------------- kernel 5: row-wise log_softmax in place --------------------
__global__ __launch_bounds__(256) void logsoftmax(float* __restrict__ out) {
  int t = blockIdx.x;
  float* row = out + (size_t)t * TAGS;
  int tid = threadIdx.x;
  float a = row[tid], b = row[tid + 256];
  float m = fmaxf(a, b);
  m = fmaxf(m, __shfl_xor(m, 1));
  m = fmaxf(m, __shfl_xor(m, 2));
  m = fmaxf(m, __shfl_xor(m, 4));
  m = fmaxf(m, __shfl_xor(m, 8));
  m = fmaxf(m, __shfl_xor(m, 16));
  m = fmaxf(m, __shfl_xor(m, 32));
  __shared__ float redm[4];
  __shared__ float reds[4];
  int wv = tid >> 6;
  if ((tid & 63) == 0) redm[wv] = m;
  __syncthreads();
  m = fmaxf(fmaxf(redm[0], redm[1]), fmaxf(redm[2], redm[3]));
  float s = __expf(a - m) + __expf(b - m);
  s += __shfl_xor(s, 1);
  s += __shfl_xor(s, 2);
  s += __shfl_xor(s, 4);
  s += __shfl_xor(s, 8);
  s += __shfl_xor(s, 16);
  s += __shfl_xor(s, 32);
  if ((tid & 63) == 0) reds[wv] = s;
  __syncthreads();
  s = reds[0] + reds[1] + reds[2] + reds[3];
  float ls = m + __logf(s);
  row[tid] = a - ls;
  row[tid + 256] = b - ls;
}

extern "C" void kernel_launch(void* const* d_in, const int* in_sizes, int n_in,
                              void* d_out, int out_size, void* d_ws, size_t ws_size,
                              hipStream_t stream) {
  (void)in_sizes; (void)n_in; (void)out_size; (void)ws_size;
  const float* emb    = (const float*)d_in[0];
  const float* w_ih_f = (const float*)d_in[1];
  const float* w_hh_f = (const float*)d_in[2];
  const float* b_f    = (const float*)d_in[3];
  const float* w_ih_b = (const float*)d_in[4];
  const float* w_hh_b = (const float*)d_in[5];
  const float* b_b    = (const float*)d_in[6];
  const float* w_out  = (const float*)d_in[7];
  const float* b_out  = (const float*)d_in[8];
  const int*   ids    = (const int*)d_in[9];
  const int*   seg    = (const int*)d_in[10];
  float* out = (float*)d_out;

  char* ws = (char*)d_ws;
  float*    embeds = (float*)ws;                                       // 8 MB
  float*    xg     = (float*)(ws + (8ll << 20));                       // 128 MB
  unsigned* hbuf   = (unsigned*)(ws + (8ll << 20) + (128ll << 20));    // 32 MB

  init_sentinel<<<2048, 256, 0, stream>>>(hbuf, 2 * SEQ * HID);
  embed_pool<<<SEQ, 256, 0, stream>>>(emb, ids, seg, embeds);
  dim3 g2(G4H / 64, SEQ / 64, 2);
  xg_gemm<<<g2, 256, 0, stream>>>(embeds, w_ih_f, b_f, w_ih_b, b_b, xg);
  lstm_scan<<<256, 64, 0, stream>>>(w_hh_f, w_hh_b, xg, hbuf);
  dim3 g4(TAGS / 128, SEQ / 64);
  out_gemm<<<g4, 256, 0, stream>>>(hbuf, w_out, b_out, out);
  logsoftmax<<<SEQ, 256, 0, stream>>>(out);
}